// Round 4
// baseline (6091.220 us; speedup 1.0000x reference)
//
#include <hip/hip_runtime.h>

#define TT 512
#define II 128
#define HH 1024
#define BB 64

typedef __attribute__((ext_vector_type(8))) short bf16x8;
typedef __attribute__((ext_vector_type(4))) float f32x4;

__device__ __forceinline__ unsigned short f2bf(float f) {
  unsigned u = __builtin_bit_cast(unsigned, f);
  u += 0x7fffu + ((u >> 16) & 1u);   // round-to-nearest-even
  return (unsigned short)(u >> 16);
}

__device__ __forceinline__ bf16x8 load8f_bf(const float* p) {
  const f32x4* q = (const f32x4*)p;
  f32x4 a = q[0];
  f32x4 b = q[1];
  bf16x8 r;
  r[0] = (short)f2bf(a[0]); r[1] = (short)f2bf(a[1]);
  r[2] = (short)f2bf(a[2]); r[3] = (short)f2bf(a[3]);
  r[4] = (short)f2bf(b[0]); r[5] = (short)f2bf(b[1]);
  r[6] = (short)f2bf(b[2]); r[7] = (short)f2bf(b[3]);
  return r;
}

__device__ __forceinline__ float sigm(float v) { return 1.f / (1.f + __expf(-v)); }
__device__ __forceinline__ float tanh_f(float v) { return 2.f / (1.f + __expf(-2.f * v)) - 1.f; }

// R1-verified coherence recipe (fastest of rounds 0-3):
//   producers: sc0sc1 write-through stores (land at LLC, acked by vmcnt)
//   consumers: PLAIN cached loads + one cheap agent-acquire (inv-only) per
//              step inside the barrier.
// R3 proved the alternative (agent-atomic h loads, no fence) is 0.9 us/step
// SLOWER: every h read went to LLC instead of hitting L2 (8 WGs/XCD share
// each h line). Do not switch h loads off the plain-load path again.
__device__ __forceinline__ void st_short_sc(unsigned short* p, unsigned short v) {
  unsigned vv = v;
  asm volatile("global_store_short %0, %1, off sc0 sc1" :: "v"(p), "v"(vv) : "memory");
}
__device__ __forceinline__ void st_dword_sc(float* p, float v) {
  asm volatile("global_store_dword %0, %1, off sc0 sc1" :: "v"(p), "v"(v) : "memory");
}

// Monotonic 16-way-split group barrier: 128 WGs per group, 16 counters
// (64 B apart) -> 8 same-address RMWs per counter per step (vs 128-way
// serialization on a single counter). Counters are monotone (+8/step each);
// target for barrier #b is 8*b. No reset, no winner, no publish hop.
// Wave 0 polls all 16 counters lane-parallel. Acquire fence (buffer_inv,
// invalidate-only, no L2 writeback) after detection, as in R1.
__device__ __forceinline__ void group_barrier(int* bar, int g, int rank, int tgt) {
  __syncthreads();
  if (threadIdx.x < 64) {
    const int ln = threadIdx.x;
    if (ln == (rank & 15)) {
      __hip_atomic_fetch_add(bar + (g * 16 + ln) * 16, 1,
          __ATOMIC_RELAXED, __HIP_MEMORY_SCOPE_AGENT);
    }
    bool ok;
    do {
      int v = tgt;
      if (ln < 16)
        v = __hip_atomic_load(bar + (g * 16 + ln) * 16,
            __ATOMIC_RELAXED, __HIP_MEMORY_SCOPE_AGENT);
      ok = __all(v >= tgt);
      if (!ok) __builtin_amdgcn_s_sleep(1);
    } while (!ok);
    __builtin_amdgcn_fence(__ATOMIC_ACQUIRE, "agent");  // inv only
  }
  __syncthreads();
}

// 256 WGs x 512 threads (8 waves), 1 WG/CU. NEW GEOMETRY (round 4):
// 2 groups x 128 WGs; group g owns batches [32g, 32g+32); WG owns 8 hidden
// units per layer (ubase = rank*8). Rationale: rounds 0-3 proved the
// allocator caps at 128 VGPRs regardless of attributes, and the old
// 16-unit/WG geometry demanded 144 VGPRs of weights alone -> forced
// spill/remat whose L2-latency sat inside the MFMA phase of all 512 serial
// steps (invisible to FETCH_SIZE: L2 hits). New per-WG weight footprint is
// 200 KB = 88 KB in VGPRs (layer0 waves: 5 kt = 40 VGPR; layer1 waves:
// 6 kt = 48 VGPR) + 112 KB in LDS (= the proven 114688 B dynamic alloc).
// Everything is resident; no in-loop weight traffic at all.
// Waves 0-3: layer0 (K=1152, 4-way split, 9 kt each: 5 VGPR + 4 LDS).
// Waves 4-7: layer1 (K=2048, 4-way split, 16 kt each: 6 VGPR + 10 LDS).
// M=32 batches -> 2 A-fragments (mt=0,1) per kt, acc[2][2].
__global__ __attribute__((amdgpu_waves_per_eu(2, 2))) __launch_bounds__(512)
void lstm_persistent(
    const float* __restrict__ x, const float* __restrict__ h0,
    const float* __restrict__ c0,
    const float* __restrict__ Wih0, const float* __restrict__ Whh0,
    const float* __restrict__ bih0, const float* __restrict__ bhh0,
    const float* __restrict__ Wih1, const float* __restrict__ Whh1,
    const float* __restrict__ bih1, const float* __restrict__ bhh1,
    const float* __restrict__ Wfc, const float* __restrict__ bfc,
    float* __restrict__ out, unsigned short* __restrict__ hbuf, int* __restrict__ bar)
{
  const int tid  = threadIdx.x;
  const int lane = tid & 63;
  const int wv   = tid >> 6;         // 0..7
  const int L    = wv >> 2;          // 0: layer0 waves, 1: layer1 waves
  const int kwv  = wv & 3;           // K-split index within layer
  const int bid  = blockIdx.x;
  const int g    = bid >> 7;         // 2 groups
  const int rank = bid & 127;        // 128 WGs per group
  const int gbase = g * 32;          // 32 batches per group
  const int ubase = rank * 8;        // 8 units per WG per layer

  unsigned short* h1s = hbuf;                  // [2][64][1024] bf16 double-buffered
  unsigned short* h2s = hbuf + 2 * BB * HH;

  __shared__ float lds_part[2][4][32][33];     // [layer][kwv][gate-row][batch pad33]
  __shared__ float lds_bias[64];               // [layer][32 gate-rows]
  __shared__ float lds_out[32];
  extern __shared__ __align__(16) unsigned short lds_w[];  // 114688 B weight frags

  const int n  = lane & 15;
  const int ko = (lane >> 4) * 8;

  // ---- pack weights: VGPRs (low kt) + LDS (high kt); fully resident ----
  // LDS layout: layer0 frags [0,2048): ((kwv*4+(kt-5))*2+nt)*64+lane
  //             layer1 frags [2048,7168): 2048+((kwv*10+(kt-6))*2+nt)*64+lane
  bf16x8 w[2][6];
  if (L == 0) {
#pragma unroll
    for (int nt = 0; nt < 2; ++nt) {
      int r = nt * 16 + n;                       // local row: unit=r>>2, gate=r&3
      int R = (r & 3) * HH + ubase + (r >> 2);   // gate*H + unit (i,f,g,o)
#pragma unroll
      for (int kt = 0; kt < 9; ++kt) {
        int c = kwv * 288 + kt * 32 + ko;        // col in [0,1152)
        const float* src = (c < II) ? (Wih0 + (size_t)R * II + c)
                                    : (Whh0 + (size_t)R * HH + (c - II));
        bf16x8 f = load8f_bf(src);
        if (kt < 5) {
          w[nt][kt] = f;
        } else {
          ((bf16x8*)lds_w)[((kwv * 4 + (kt - 5)) * 2 + nt) * 64 + lane] = f;
        }
      }
    }
  } else {
#pragma unroll
    for (int nt = 0; nt < 2; ++nt) {
      int r = nt * 16 + n;
      int R = (r & 3) * HH + ubase + (r >> 2);
#pragma unroll
      for (int kt = 0; kt < 16; ++kt) {
        int c = kwv * 512 + kt * 32 + ko;        // col in [0,2048)
        const float* src = (c < HH) ? (Wih1 + (size_t)R * HH + c)
                                    : (Whh1 + (size_t)R * HH + (c - HH));
        bf16x8 f = load8f_bf(src);
        if (kt < 6) {
          w[nt][kt] = f;
        } else {
          ((bf16x8*)lds_w)[2048 + ((kwv * 10 + (kt - 6)) * 2 + nt) * 64 + lane] = f;
        }
      }
    }
  }

  // combined biases -> LDS (row r of layer Lr: unit=r>>2, gate=r&3)
  if (tid < 64) {
    int Lr = tid >> 5, r = tid & 31;
    int R = (r & 3) * HH + ubase + (r >> 2);
    lds_bias[tid] = (Lr == 0) ? (bih0[R] + bhh0[R]) : (bih1[R] + bhh1[R]);
  }

  // epilogue mapping: 512 threads = 2 layers x 32 batches x 8 units
  const int eL = tid >> 8;
  const int eu = tid & 7;
  const int em = (tid >> 3) & 31;
  const int b_e = gbase + em;
  const int u_e = ubase + eu;
  float c_st = c0[eL * BB * HH + b_e * HH + u_e];
  const float wfc_r = Wfc[u_e];

  // init h double-buffers: slot 1 <- h0 (write-through; read cross-XCD at p=0/1)
  if (rank < 32) {
    int b = gbase + rank;
    int u = tid * 2;  // 512 threads x 2 units = 1024 = HH exactly
    unsigned p1 = (unsigned)f2bf(h0[0 * BB * HH + b * HH + u]) |
                  ((unsigned)f2bf(h0[0 * BB * HH + b * HH + u + 1]) << 16);
    unsigned p2 = (unsigned)f2bf(h0[1 * BB * HH + b * HH + u]) |
                  ((unsigned)f2bf(h0[1 * BB * HH + b * HH + u + 1]) << 16);
    st_dword_sc((float*)(h1s + BB * HH + b * HH + u), __builtin_bit_cast(float, p1));
    st_dword_sc((float*)(h2s + BB * HH + b * HH + u), __builtin_bit_cast(float, p2));
  }
  // init out with b_fc at the LLC (out atomics accumulate there)
  if (rank == 0) {
    float bf = bfc[0];
    for (int i = tid; i < 32 * TT; i += 512)
      st_dword_sc(&out[(gbase + (i >> 9)) * TT + (i & 511)], bf);
  }
  asm volatile("s_waitcnt vmcnt(0)" ::: "memory");  // drain asm sc stores

  group_barrier(bar, g, rank, 8 * 1);

  const int bA0 = gbase + n;        // A-fragment batches (m = lane&15)
  const int bA1 = gbase + 16 + n;

  for (int p = 0; p <= TT; ++p) {
    const bool l0act = (p < TT);
    const bool l1act = (p >= 1);
    const unsigned short* h1r = h1s + ((p - 1) & 1) * (BB * HH);  // h1[p-1]
    const unsigned short* h2r = h2s + (p & 1) * (BB * HH);        // h2[p-2]

    f32x4 acc[2][2];  // [mt][nt]
#pragma unroll
    for (int mt = 0; mt < 2; ++mt)
#pragma unroll
      for (int nt = 0; nt < 2; ++nt) acc[mt][nt] = (f32x4){0.f, 0.f, 0.f, 0.f};

    if (L == 0) {
      if (l0act) {
        if (kwv == 0) {
#pragma unroll
          for (int kt = 0; kt < 4; ++kt) {             // cols 0..127: from x (fp32)
            bf16x8 a0 = load8f_bf(x + ((size_t)bA0 * TT + p) * II + kt * 32 + ko);
            bf16x8 a1 = load8f_bf(x + ((size_t)bA1 * TT + p) * II + kt * 32 + ko);
#pragma unroll
            for (int nt = 0; nt < 2; ++nt) {
              acc[0][nt] = __builtin_amdgcn_mfma_f32_16x16x32_bf16(a0, w[nt][kt], acc[0][nt], 0, 0, 0);
              acc[1][nt] = __builtin_amdgcn_mfma_f32_16x16x32_bf16(a1, w[nt][kt], acc[1][nt], 0, 0, 0);
            }
          }
#pragma unroll
          for (int kt = 4; kt < 9; ++kt) {             // cols 128..287: h1[p-1]
            int off = kt * 32 + ko - II;
            bf16x8 a0 = *(const bf16x8*)(h1r + (size_t)bA0 * HH + off);
            bf16x8 a1 = *(const bf16x8*)(h1r + (size_t)bA1 * HH + off);
#pragma unroll
            for (int nt = 0; nt < 2; ++nt) {
              bf16x8 wf = (kt < 5) ? w[nt][kt]
                  : ((const bf16x8*)lds_w)[((kwv * 4 + (kt - 5)) * 2 + nt) * 64 + lane];
              acc[0][nt] = __builtin_amdgcn_mfma_f32_16x16x32_bf16(a0, wf, acc[0][nt], 0, 0, 0);
              acc[1][nt] = __builtin_amdgcn_mfma_f32_16x16x32_bf16(a1, wf, acc[1][nt], 0, 0, 0);
            }
          }
        } else {
#pragma unroll
          for (int kt = 0; kt < 9; ++kt) {             // all from h1[p-1]
            int off = kwv * 288 + kt * 32 + ko - II;
            bf16x8 a0 = *(const bf16x8*)(h1r + (size_t)bA0 * HH + off);
            bf16x8 a1 = *(const bf16x8*)(h1r + (size_t)bA1 * HH + off);
#pragma unroll
            for (int nt = 0; nt < 2; ++nt) {
              bf16x8 wf = (kt < 5) ? w[nt][kt]
                  : ((const bf16x8*)lds_w)[((kwv * 4 + (kt - 5)) * 2 + nt) * 64 + lane];
              acc[0][nt] = __builtin_amdgcn_mfma_f32_16x16x32_bf16(a0, wf, acc[0][nt], 0, 0, 0);
              acc[1][nt] = __builtin_amdgcn_mfma_f32_16x16x32_bf16(a1, wf, acc[1][nt], 0, 0, 0);
            }
          }
        }
      }
    } else {
      if (l1act) {
        // kwv 0,1 read h1[p-1]; kwv 2,3 read h2[p-2]
        const unsigned short* hb = (kwv < 2) ? h1r : h2r;
        const int kbase = (kwv & 1) * 512;
#pragma unroll
        for (int kt = 0; kt < 16; ++kt) {
          int off = kbase + kt * 32 + ko;
          bf16x8 a0 = *(const bf16x8*)(hb + (size_t)bA0 * HH + off);
          bf16x8 a1 = *(const bf16x8*)(hb + (size_t)bA1 * HH + off);
#pragma unroll
          for (int nt = 0; nt < 2; ++nt) {
            bf16x8 wf = (kt < 6) ? w[nt][kt]
                : ((const bf16x8*)lds_w)[2048 + ((kwv * 10 + (kt - 6)) * 2 + nt) * 64 + lane];
            acc[0][nt] = __builtin_amdgcn_mfma_f32_16x16x32_bf16(a0, wf, acc[0][nt], 0, 0, 0);
            acc[1][nt] = __builtin_amdgcn_mfma_f32_16x16x32_bf16(a1, wf, acc[1][nt], 0, 0, 0);
          }
        }
      }
    }

    // stage partials to LDS (D layout: n-row = lane&15, m = (lane>>4)*4 + reg)
    {
      const bool act = (L == 0) ? l0act : l1act;
      if (act) {
        const int m0 = (lane >> 4) * 4;
#pragma unroll
        for (int nt = 0; nt < 2; ++nt) {
          int row = nt * 16 + n;
#pragma unroll
          for (int mt = 0; mt < 2; ++mt)
#pragma unroll
            for (int r = 0; r < 4; ++r)
              lds_part[L][kwv][row][mt * 16 + m0 + r] = acc[mt][nt][r];
        }
      }
    }
    if (tid < 32) lds_out[tid] = 0.f;
    __syncthreads();

    // epilogue: 1 (layer,unit,batch) per thread; c-state in register
    const bool eact = (eL == 0) ? l0act : l1act;
    if (eact) {
      float pre[4];
#pragma unroll
      for (int q = 0; q < 4; ++q) {
        float s = lds_bias[eL * 32 + eu * 4 + q];
#pragma unroll
        for (int w2 = 0; w2 < 4; ++w2)
          s += lds_part[eL][w2][eu * 4 + q][em];
        pre[q] = s;
      }
      float iv = sigm(pre[0]);
      float fv = sigm(pre[1]);
      float gv = tanh_f(pre[2]);
      float ov = sigm(pre[3]);
      c_st = fv * c_st + iv * gv;
      float hv = ov * tanh_f(c_st);
      // pack 2 adjacent units (even/odd eu = adjacent lanes) into one 4B store
      unsigned short hb16 = f2bf(hv);
      int partner = __shfl_xor((int)hb16, 1);
      unsigned short* hdst = (eL == 0) ? (h1s + (p & 1) * (BB * HH))          // h1[p]
                                       : (h2s + ((p - 1) & 1) * (BB * HH));   // h2[p-1]
      if ((lane & 1) == 0) {
        unsigned pk = (unsigned)hb16 | ((unsigned)partner << 16);
        st_dword_sc((float*)(hdst + b_e * HH + u_e), __builtin_bit_cast(float, pk));
      }
      if (eL == 1) atomicAdd(&lds_out[em], hv * wfc_r);                       // FC partial
    }
    // drain asm sc stores before the arrive (invisible to waitcnt pass)
    asm volatile("s_waitcnt vmcnt(0)" ::: "memory");
    __syncthreads();
    if (l1act && tid < 32)
      atomicAdd(&out[(gbase + tid) * TT + (p - 1)], lds_out[tid]);  // fire-and-forget

    if (p < TT) group_barrier(bar, g, rank, 8 * (p + 2));
  }
}

extern "C" void kernel_launch(void* const* d_in, const int* in_sizes, int n_in,
                              void* d_out, int out_size, void* d_ws, size_t ws_size,
                              hipStream_t stream) {
  (void)in_sizes; (void)n_in; (void)out_size; (void)ws_size;
  hipMemsetAsync(d_ws, 0, 4096, stream);   // 2 groups x 16 counters x 64B
  int* bar = (int*)d_ws;
  unsigned short* hbuf = (unsigned short*)((char*)d_ws + 4096);  // 512 KB h buffers
  hipLaunchKernelGGL(lstm_persistent, dim3(256), dim3(512), 114688, stream,
      (const float*)d_in[0], (const float*)d_in[1], (const float*)d_in[2],
      (const float*)d_in[3], (const float*)d_in[4], (const float*)d_in[5],
      (const float*)d_in[6], (const float*)d_in[7], (const float*)d_in[8],
      (const float*)d_in[9], (const float*)d_in[10], (const float*)d_in[11],
      (const float*)d_in[12], (float*)d_out, hbuf, bar);
}

// Round 5
// 3804.254 us; speedup vs baseline: 1.6012x; 1.6012x over previous
//
#include <hip/hip_runtime.h>

#define TT 512
#define II 128
#define HH 1024
#define BB 64

typedef __attribute__((ext_vector_type(8))) short bf16x8;
typedef __attribute__((ext_vector_type(4))) float f32x4;

__device__ __forceinline__ unsigned short f2bf(float f) {
  unsigned u = __builtin_bit_cast(unsigned, f);
  u += 0x7fffu + ((u >> 16) & 1u);   // round-to-nearest-even
  return (unsigned short)(u >> 16);
}

__device__ __forceinline__ bf16x8 load8f_bf(const float* p) {
  const f32x4* q = (const f32x4*)p;
  f32x4 a = q[0];
  f32x4 b = q[1];
  bf16x8 r;
  r[0] = (short)f2bf(a[0]); r[1] = (short)f2bf(a[1]);
  r[2] = (short)f2bf(a[2]); r[3] = (short)f2bf(a[3]);
  r[4] = (short)f2bf(b[0]); r[5] = (short)f2bf(b[1]);
  r[6] = (short)f2bf(b[2]); r[7] = (short)f2bf(b[3]);
  return r;
}

__device__ __forceinline__ float sigm(float v) { return 1.f / (1.f + __expf(-v)); }
__device__ __forceinline__ float tanh_f(float v) { return 2.f / (1.f + __expf(-2.f * v)) - 1.f; }

// R1-verified coherence recipe (fastest of rounds 0-4):
//   producers: sc0sc1 write-through stores (land at LLC, acked by vmcnt)
//   consumers: PLAIN cached loads + agent-acquire (buffer_inv, invalidate-
//              only: clean lines dropped, DIRTY lines — incl. compiler
//              scratch spills — survive) once per step inside the barrier.
// R3 proved agent-atomic h loads are +0.9 us/step (LLC every read, no L2
// sharing). R4 proved weight-spill was never the cost (no-spill geometry
// regressed). Do not revisit either.
__device__ __forceinline__ void st_short_sc(unsigned short* p, unsigned short v) {
  unsigned vv = v;
  asm volatile("global_store_short %0, %1, off sc0 sc1" :: "v"(p), "v"(vv) : "memory");
}
__device__ __forceinline__ void st_dword_sc(float* p, float v) {
  asm volatile("global_store_dword %0, %1, off sc0 sc1" :: "v"(p), "v"(v) : "memory");
}

// Monotonic 16-way-split group barrier: 64 WGs per group, 16 counters
// (64 B apart; rank&15 -> counter) so the per-step arrive phase is 4
// same-address LLC RMWs per counter in parallel across 16 lines, instead
// of R1's 64 serialized RMWs on ONE line (TCC handles same-line atomics
// serially; that was ~1.5-3 us of R1's 8 us step). Counters are monotone
// (+4/step each); target for barrier #b is 4*b. No reset, no winner branch,
// no publish hop. Wave 0 arrives (one lane) and polls all 16 counters
// lane-parallel; acquire fence (inv-only) after detect, as in R1.
__device__ __forceinline__ void group_barrier(int* bar, int g, int rank, int tgt) {
  __syncthreads();
  if (threadIdx.x < 64) {
    const int ln = threadIdx.x;
    if (ln == (rank & 15)) {
      __hip_atomic_fetch_add(bar + (g * 16 + ln) * 16, 1,
          __ATOMIC_RELAXED, __HIP_MEMORY_SCOPE_AGENT);
    }
    bool ok;
    do {
      int v = tgt;
      if (ln < 16)
        v = __hip_atomic_load(bar + (g * 16 + ln) * 16,
            __ATOMIC_RELAXED, __HIP_MEMORY_SCOPE_AGENT);
      ok = __all(v >= tgt);
      if (!ok) __builtin_amdgcn_s_sleep(1);
    } while (!ok);
    __builtin_amdgcn_fence(__ATOMIC_ACQUIRE, "agent");  // inv only (no wbl2)
  }
  __syncthreads();
}

// 256 WGs x 512 threads (8 waves), 1 WG/CU. 4 groups x 64 WGs; group g owns
// batches [16g,16g+16). WG owns 16 hidden units per layer.
// Waves 0-3: layer0 (K=1152, 4-way split, 9 kt each, weights in VGPRs).
// Waves 4-7: layer1 (K=2048, 4-way split, 16 kt: 9 in VGPRs + 7 in LDS).
//
// GEOMETRY IS SETTLED (rounds 0-4): 4x64 beats 2x128 even though 4x64
// over-asks VGPRs (144 weight regs vs 128 budget -> ~150 KB/WG compiler
// spill). The spill lines are dirty-resident in L2 (survive the per-step
// buffer_inv) and reload as L2 hits; whereas 2x128 (weights fully resident,
// VGPR=88) doubles per-WG h-read volume and the barrier domain, costing
// +3.7 us/step. Leave the spill alone.
__global__ __attribute__((amdgpu_waves_per_eu(2, 2))) __launch_bounds__(512)
void lstm_persistent(
    const float* __restrict__ x, const float* __restrict__ h0,
    const float* __restrict__ c0,
    const float* __restrict__ Wih0, const float* __restrict__ Whh0,
    const float* __restrict__ bih0, const float* __restrict__ bhh0,
    const float* __restrict__ Wih1, const float* __restrict__ Whh1,
    const float* __restrict__ bih1, const float* __restrict__ bhh1,
    const float* __restrict__ Wfc, const float* __restrict__ bfc,
    float* __restrict__ out, unsigned short* __restrict__ hbuf, int* __restrict__ bar)
{
  const int tid  = threadIdx.x;
  const int lane = tid & 63;
  const int wv   = tid >> 6;         // 0..7
  const int L    = wv >> 2;          // 0: layer0 waves, 1: layer1 waves
  const int kwv  = wv & 3;           // K-split index within layer
  const int bid  = blockIdx.x;
  const int g    = bid >> 6;
  const int rank = bid & 63;
  const int gbase = g * 16;
  const int ubase = rank * 16;

  unsigned short* h1s = hbuf;                  // [2][64][1024] bf16 double-buffered (layer0 h)
  unsigned short* h2s = hbuf + 2 * BB * HH;    // layer1 h

  __shared__ float lds_part[2][4][64][17];     // [layer][kwv][gate-row][batch pad17]
  __shared__ float lds_bias[128];
  __shared__ float lds_out[16];
  extern __shared__ __align__(16) unsigned short lds_w[];  // 4*7*4*64 frags * 16B = 114688B

  const int n  = lane & 15;
  const int ko = (lane >> 4) * 8;

  // ---- pack weights: registers (both layers) + LDS (layer1 kt 9..15) ----
  bf16x8 w[4][9];
  if (L == 0) {
#pragma unroll
    for (int nt = 0; nt < 4; ++nt) {
      int r = nt * 16 + n;                       // local row: unit=r>>2, gate=r&3
      int R = (r & 3) * HH + ubase + (r >> 2);   // gate*H + unit (i,f,g,o)
#pragma unroll
      for (int kt = 0; kt < 9; ++kt) {
        int c = kwv * 288 + kt * 32 + ko;        // col in [0,1152)
        const float* src = (c < II) ? (Wih0 + (size_t)R * II + c)
                                    : (Whh0 + (size_t)R * HH + (c - II));
        w[nt][kt] = load8f_bf(src);
      }
    }
  } else {
#pragma unroll
    for (int nt = 0; nt < 4; ++nt) {
      int r = nt * 16 + n;
      int R = (r & 3) * HH + ubase + (r >> 2);
#pragma unroll
      for (int kt = 0; kt < 16; ++kt) {
        int c = kwv * 512 + kt * 32 + ko;        // col in [0,2048)
        const float* src = (c < HH) ? (Wih1 + (size_t)R * HH + c)
                                    : (Whh1 + (size_t)R * HH + (c - HH));
        bf16x8 f = load8f_bf(src);
        if (kt < 9) {
          w[nt][kt] = f;
        } else {
          int fi = ((kwv * 7 + (kt - 9)) * 4 + nt) * 64 + lane;
          ((bf16x8*)lds_w)[fi] = f;
        }
      }
    }
  }

  // combined biases -> LDS
  if (tid < 128) {
    int Lr = tid >> 6, r = tid & 63;
    int R = (r & 3) * HH + ubase + (r >> 2);
    lds_bias[tid] = (Lr == 0) ? (bih0[R] + bhh0[R]) : (bih1[R] + bhh1[R]);
  }

  // epilogue mapping: 512 threads = 2 layers x 16 units x 16 batches
  const int eL = tid >> 8;
  const int eu = tid & 15;
  const int em = (tid >> 4) & 15;
  const int b_e = gbase + em;
  const int u_e = ubase + eu;
  float c_st = c0[eL * BB * HH + b_e * HH + u_e];
  const float wfc_r = Wfc[u_e];

  // init h double-buffers: slot 1 <- h0 (write-through: read cross-XCD at p=0/1)
  if (rank < 16) {
    int b = gbase + rank;
    for (int u = tid; u < HH; u += 512) {
      st_short_sc(&h1s[BB * HH + b * HH + u], f2bf(h0[0 * BB * HH + b * HH + u]));
      st_short_sc(&h2s[BB * HH + b * HH + u], f2bf(h0[1 * BB * HH + b * HH + u]));
    }
  }
  // init out with b_fc (atomics accumulate onto it at LLC -> init must be at LLC too)
  if (rank == 0) {
    float bf = bfc[0];
    for (int i = tid; i < 16 * TT; i += 512)
      st_dword_sc(&out[(gbase + (i >> 9)) * TT + (i & 511)], bf);
  }
  asm volatile("s_waitcnt vmcnt(0)" ::: "memory");  // drain asm sc1 stores (invisible to waitcnt pass)

  group_barrier(bar, g, rank, 4 * 1);

  const int bA = gbase + n;   // A-fragment batch (m = lane&15)

  for (int p = 0; p <= TT; ++p) {
    const bool l0act = (p < TT);
    const bool l1act = (p >= 1);
    const unsigned short* h1r = h1s + ((p - 1) & 1) * (BB * HH);  // h1[p-1]
    const unsigned short* h2r = h2s + (p & 1) * (BB * HH);        // h2[p-2]

    f32x4 acc[4];
#pragma unroll
    for (int nt = 0; nt < 4; ++nt) acc[nt] = (f32x4){0.f, 0.f, 0.f, 0.f};

    if (L == 0) {
      if (l0act) {
        if (kwv == 0) {
#pragma unroll
          for (int kt = 0; kt < 4; ++kt) {             // cols 0..127: from x (fp32)
            bf16x8 a = load8f_bf(x + ((size_t)bA * TT + p) * II + kt * 32 + ko);
#pragma unroll
            for (int nt = 0; nt < 4; ++nt)
              acc[nt] = __builtin_amdgcn_mfma_f32_16x16x32_bf16(a, w[nt][kt], acc[nt], 0, 0, 0);
          }
#pragma unroll
          for (int kt = 4; kt < 9; ++kt) {             // cols 128..287: h1[p-1]
            bf16x8 a = *(const bf16x8*)(h1r + (size_t)bA * HH + (kt * 32 + ko - II));
#pragma unroll
            for (int nt = 0; nt < 4; ++nt)
              acc[nt] = __builtin_amdgcn_mfma_f32_16x16x32_bf16(a, w[nt][kt], acc[nt], 0, 0, 0);
          }
        } else {
#pragma unroll
          for (int kt = 0; kt < 9; ++kt) {             // all from h1[p-1]
            int off = kwv * 288 + kt * 32 + ko - II;
            bf16x8 a = *(const bf16x8*)(h1r + (size_t)bA * HH + off);
#pragma unroll
            for (int nt = 0; nt < 4; ++nt)
              acc[nt] = __builtin_amdgcn_mfma_f32_16x16x32_bf16(a, w[nt][kt], acc[nt], 0, 0, 0);
          }
        }
      }
    } else {
      if (l1act) {
        // kwv 0,1 read h1[p-1]; kwv 2,3 read h2[p-2]
        const unsigned short* hb = (kwv < 2) ? h1r : h2r;
        const int kbase = (kwv & 1) * 512;
#pragma unroll
        for (int kt = 0; kt < 9; ++kt) {
          bf16x8 a = *(const bf16x8*)(hb + (size_t)bA * HH + kbase + kt * 32 + ko);
#pragma unroll
          for (int nt = 0; nt < 4; ++nt)
            acc[nt] = __builtin_amdgcn_mfma_f32_16x16x32_bf16(a, w[nt][kt], acc[nt], 0, 0, 0);
        }
#pragma unroll
        for (int kt = 9; kt < 16; ++kt) {
          bf16x8 a = *(const bf16x8*)(hb + (size_t)bA * HH + kbase + kt * 32 + ko);
#pragma unroll
          for (int nt = 0; nt < 4; ++nt) {
            bf16x8 wf = ((const bf16x8*)lds_w)[((kwv * 7 + (kt - 9)) * 4 + nt) * 64 + lane];
            acc[nt] = __builtin_amdgcn_mfma_f32_16x16x32_bf16(a, wf, acc[nt], 0, 0, 0);
          }
        }
      }
    }

    // stage partials to LDS (D layout: n-row = lane&15, m = (lane>>4)*4 + reg)
    {
      const bool act = (L == 0) ? l0act : l1act;
      if (act) {
        const int m0 = (lane >> 4) * 4;
#pragma unroll
        for (int nt = 0; nt < 4; ++nt) {
          int row = nt * 16 + n;
#pragma unroll
          for (int r = 0; r < 4; ++r)
            lds_part[L][kwv][row][m0 + r] = acc[nt][r];
        }
      }
    }
    if (tid < 16) lds_out[tid] = 0.f;
    __syncthreads();

    // epilogue: 1 (layer,unit,batch) per thread; c-state in register
    const bool eact = (eL == 0) ? l0act : l1act;
    if (eact) {
      float pre[4];
#pragma unroll
      for (int q = 0; q < 4; ++q) {
        float s = lds_bias[eL * 64 + eu * 4 + q];
#pragma unroll
        for (int w2 = 0; w2 < 4; ++w2)
          s += lds_part[eL][w2][eu * 4 + q][em];
        pre[q] = s;
      }
      float iv = sigm(pre[0]);
      float fv = sigm(pre[1]);
      float gv = tanh_f(pre[2]);
      float ov = sigm(pre[3]);
      c_st = fv * c_st + iv * gv;
      float hv = ov * tanh_f(c_st);
      if (eL == 0) {
        st_short_sc(&h1s[(p & 1) * (BB * HH) + b_e * HH + u_e], f2bf(hv));        // h1[p]
      } else {
        st_short_sc(&h2s[((p - 1) & 1) * (BB * HH) + b_e * HH + u_e], f2bf(hv));  // h2[p-1]
        atomicAdd(&lds_out[em], hv * wfc_r);                                      // FC partial
      }
    }
    // drain asm sc1 stores before the barrier's s_barrier (per-wave; the
    // compiler's waitcnt-insertion pass cannot see inline-asm vmem ops).
    asm volatile("s_waitcnt vmcnt(0)" ::: "memory");
    __syncthreads();
    if (l1act && tid < 16)
      atomicAdd(&out[(gbase + tid) * TT + (p - 1)], lds_out[tid]);

    if (p < TT) group_barrier(bar, g, rank, 4 * (p + 2));
  }
}

extern "C" void kernel_launch(void* const* d_in, const int* in_sizes, int n_in,
                              void* d_out, int out_size, void* d_ws, size_t ws_size,
                              hipStream_t stream) {
  (void)in_sizes; (void)n_in; (void)out_size; (void)ws_size;
  hipMemsetAsync(d_ws, 0, 4096, stream);   // 4 groups x 16 counters x 64B = 4 KB barrier state
  int* bar = (int*)d_ws;
  unsigned short* hbuf = (unsigned short*)((char*)d_ws + 4096);  // 512 KB h buffers
  hipLaunchKernelGGL(lstm_persistent, dim3(256), dim3(512), 114688, stream,
      (const float*)d_in[0], (const float*)d_in[1], (const float*)d_in[2],
      (const float*)d_in[3], (const float*)d_in[4], (const float*)d_in[5],
      (const float*)d_in[6], (const float*)d_in[7], (const float*)d_in[8],
      (const float*)d_in[9], (const float*)d_in[10], (const float*)d_in[11],
      (const float*)d_in[12], (float*)d_out, hbuf, bar);
}